// Round 6
// baseline (121.530 us; speedup 1.0000x reference)
//
#include <hip/hip_runtime.h>
#include <hip/hip_bf16.h>
#include <hip/hip_cooperative_groups.h>
#include <stdint.h>

namespace cg = cooperative_groups;

// Problem constants (fixed by reference)
#define BB 4
#define LL 256
#define WW 256
#define HH 768
#define NL 10
#define LT 16           // L-rows per score block
#define WT 64           // W-cols per score block

typedef __attribute__((ext_vector_type(8))) short bf16x8;   // 8 bf16 (4 VGPRs)
typedef __attribute__((ext_vector_type(4))) float f32x4;    // MFMA C/D

__device__ inline unsigned short f2bf(float x) {            // RNE via HW cvt
    return __builtin_bit_cast(unsigned short, __float2bfloat16(x));
}

// ---------------------------------------------------------------------------
// One cooperative kernel, 3 phases, grid 256 x 256 (1 block/CU co-resident):
//  P1: gather emb_a rows + cvt both operands to bf16 tables (3 MB, L2-fit)
//  P2: u-tile MFMA + masked exp + label buckets (unnormalized, D = sum_k s_k)
//  P3: combine partials, normalize, 10-row epilogue + residual
// ---------------------------------------------------------------------------
__global__ __launch_bounds__(256, 1) void fused_kernel(
    const int* __restrict__ word_seq,           // [B,W]
    const float* __restrict__ hidden,           // [B,L,H]
    const int* __restrict__ label,              // [B,L,W]
    const float* __restrict__ mask,             // [B,L,W]
    const float* __restrict__ emb_a,            // [50000,H]
    const float* __restrict__ emb_c,            // [10,H]
    float* __restrict__ out,                    // [B,L,H]
    unsigned short* __restrict__ hid_b,         // ws: [B*L][768] bf16
    unsigned short* __restrict__ ea_b,          // ws: [B*W][768] bf16
    float* __restrict__ s_out)                  // ws: [256][16][10]
{
    cg::grid_group grid = cg::this_grid();
    __shared__ float s_lds[LT][NL];
    __shared__ float sp[LT][NL];
    __shared__ float inv[LT];

    const int t   = threadIdx.x;
    const int bid = blockIdx.x;
    const int gi  = bid * 256 + t;              // [0, 65536)

    // ================= Phase 1: gather + bf16 convert =================
    // 196608 float4 slots per table; 3 slots/thread each.
    #pragma unroll
    for (int p = 0; p < 3; ++p) {
        int j  = p * 65536 + gi;                // [0, 196608)
        int r  = j / 192, c4 = j - r * 192;
        {
            int row  = word_seq[r];
            float4 v = reinterpret_cast<const float4*>(emb_a)[(size_t)row * 192 + c4];
            ushort4 o = { f2bf(v.x), f2bf(v.y), f2bf(v.z), f2bf(v.w) };
            reinterpret_cast<ushort4*>(ea_b)[(size_t)r * 192 + c4] = o;
        }
        {
            float4 v = reinterpret_cast<const float4*>(hidden)[j];
            ushort4 o = { f2bf(v.x), f2bf(v.y), f2bf(v.z), f2bf(v.w) };
            reinterpret_cast<ushort4*>(hid_b)[j] = o;
        }
    }
    if (t < LT * NL) ((float*)s_lds)[t] = 0.f;

    __threadfence();        // agent-release: write back L2 (cross-XCD visibility)
    grid.sync();

    // ================= Phase 2: score (MFMA + exp + buckets) =================
    {
        const int wave = t >> 6, lane = t & 63;
        const int wt = bid & 3, lt = (bid >> 2) & 15, b = bid >> 6;
        const int l0 = lt * LT;
        const int g = lane >> 4, c = lane & 15;

        // A row = lane&15 (M=l), B col = lane&15 (N=w); k-group = lane>>4.
        const int wcol = wt * WT + wave * 16 + c;
        const unsigned short* arow = hid_b + ((size_t)(b * LL) + l0 + c) * HH + g * 8;
        const unsigned short* brow = ea_b  + ((size_t)(b * WW) + wcol) * HH + g * 8;

        f32x4 acc = {0.f, 0.f, 0.f, 0.f};
        #pragma unroll
        for (int k = 0; k < 24; ++k) {
            bf16x8 a  = *reinterpret_cast<const bf16x8*>(arow + k * 32);
            bf16x8 bv = *reinterpret_cast<const bf16x8*>(brow + k * 32);
            acc = __builtin_amdgcn_mfma_f32_16x16x32_bf16(a, bv, acc, 0, 0, 0);
        }
        __syncthreads();    // s_lds zeros visible

        // C/D layout (m89): col = lane&15, row = (lane>>4)*4 + reg
        const float scale = 0.03608439182435161f;  // 1/sqrt(768)
        #pragma unroll
        for (int r = 0; r < 4; ++r) {
            int lrow = g * 4 + r;
            size_t idx = ((size_t)(b * LL) + l0 + lrow) * WW + wcol;
            float m = mask[idx];
            m = fminf(fmaxf(m, 0.f), 1.f);
            float e = __expf(acc[r] * scale) * m;
            atomicAdd(&s_lds[lrow][label[idx]], e);
        }
        __syncthreads();

        if (t < LT * NL)
            s_out[(size_t)bid * (LT * NL) + t] = ((float*)s_lds)[t];
    }

    __threadfence();        // make s_out visible across XCDs
    grid.sync();

    // ================= Phase 3: combine + epilogue =================
    {
        const int hq = bid & 3, lt = (bid >> 2) & 15, b = bid >> 6;
        const int l0 = lt * LT;
        const int h  = hq * 192 + t;

        if (t < LT * NL) {
            size_t base = ((size_t)(b * 16 + lt)) * 4 * (LT * NL);  // wt=0 slot
            float v = 0.f;
            #pragma unroll
            for (int wt = 0; wt < 4; ++wt)
                v += __hip_atomic_load(&s_out[base + wt * (LT * NL) + t],
                                       __ATOMIC_RELAXED, __HIP_MEMORY_SCOPE_AGENT);
            ((float*)sp)[t] = v;
        }
        __syncthreads();
        if (t < LT) {
            float d = 1e-10f;
            #pragma unroll
            for (int k = 0; k < NL; ++k) d += sp[t][k];
            inv[t] = 1.f / d;
        }
        __syncthreads();

        if (t < 192) {
            float ec[NL];
            #pragma unroll
            for (int k = 0; k < NL; ++k) ec[k] = emb_c[k * HH + h];
            #pragma unroll
            for (int r = 0; r < LT; ++r) {
                size_t base = ((size_t)(b * LL) + l0 + r) * HH + h;
                float acc = 0.f;
                #pragma unroll
                for (int k = 0; k < NL; ++k) acc = fmaf(sp[r][k], ec[k], acc);
                out[base] = hidden[base] + acc * inv[r];
            }
        }
    }
}

extern "C" void kernel_launch(void* const* d_in, const int* in_sizes, int n_in,
                              void* d_out, int out_size, void* d_ws, size_t ws_size,
                              hipStream_t stream) {
    const int*   word_seq = (const int*)d_in[0];
    const float* hidden   = (const float*)d_in[1];
    const int*   label    = (const int*)d_in[2];
    const float* mask     = (const float*)d_in[3];
    const float* emb_a    = (const float*)d_in[4];
    const float* emb_c    = (const float*)d_in[5];
    float*       out      = (float*)d_out;

    // Workspace carve (~3.3 MB of 600 MB):
    unsigned short* hid_b = (unsigned short*)d_ws;                 // 1024*768 bf16
    unsigned short* ea_b  = hid_b + (size_t)BB * LL * HH;          // 1024*768 bf16
    float*          s_out = (float*)(ea_b + (size_t)BB * WW * HH); // 256*160 fp32

    void* args[] = { (void*)&word_seq, (void*)&hidden, (void*)&label,
                     (void*)&mask, (void*)&emb_a, (void*)&emb_c,
                     (void*)&out, (void*)&hid_b, (void*)&ea_b, (void*)&s_out };
    hipLaunchCooperativeKernel(reinterpret_cast<void*>(fused_kernel),
                               dim3(256), dim3(256), args, 0, stream);
}

// Round 7
// 21.779 us; speedup vs baseline: 5.5801x; 5.5801x over previous
//
#include <hip/hip_runtime.h>
#include <hip/hip_bf16.h>
#include <stdint.h>

// Problem constants (fixed by reference)
#define BB 4
#define LL 256
#define WW 256
#define HH 768
#define NL 10
#define LT 16           // L-rows per score block
#define WT 64           // W-cols per score block

typedef __attribute__((ext_vector_type(8))) short bf16x8;   // 8 bf16 (4 VGPRs)
typedef __attribute__((ext_vector_type(4))) float f32x4;    // MFMA C/D

__device__ inline unsigned short f2bf(float x) {            // RNE via HW cvt
    return __builtin_bit_cast(unsigned short, __float2bfloat16(x));
}
__device__ inline bf16x8 pack8(float4 a, float4 b) {
    union { bf16x8 v; unsigned short u[8]; } r;
    r.u[0] = f2bf(a.x); r.u[1] = f2bf(a.y); r.u[2] = f2bf(a.z); r.u[3] = f2bf(a.w);
    r.u[4] = f2bf(b.x); r.u[5] = f2bf(b.y); r.u[6] = f2bf(b.z); r.u[7] = f2bf(b.w);
    return r.v;
}

// ---------------------------------------------------------------------------
// K1: fused gather + bf16 convert + u-tile MFMA + masked exp + label buckets.
// Block = (b, 16 L-rows, 64 W-cols); 4 waves, each one 16x16 C-tile.
// Fragment loads are a hand-pipelined depth-4 rotating buffer (16 x 16B loads
// in flight per lane) -> MLP-bound, not latency-serialized. No (256,2) VGPR
// clamp: __launch_bounds__(256,1) lets the pipeline live in registers.
// Writes UNNORMALIZED buckets s[16][10]; denominator D = sum_k s_k later.
// ---------------------------------------------------------------------------
__global__ __launch_bounds__(256, 1) void score_kernel(
    const int* __restrict__ word_seq,           // [B,W]
    const float* __restrict__ hidden,           // [B,L,H]
    const float* __restrict__ emb_a,            // [50000,H]
    const int* __restrict__ label,              // [B,L,W]
    const float* __restrict__ mask,             // [B,L,W]
    float* __restrict__ s_out)                  // [256 blocks][16][10]
{
    __shared__ float s_lds[LT][NL];
    const int t    = threadIdx.x;
    const int wave = t >> 6, lane = t & 63;
    const int bid  = blockIdx.x;
    const int wt = bid & 3, lt = (bid >> 2) & 15, b = bid >> 6;
    const int l0 = lt * LT;
    const int g = lane >> 4, c = lane & 15;

    if (t < LT * NL) ((float*)s_lds)[t] = 0.f;

    // A row = lane&15 (M=l), B col = lane&15 (N=w); k-group = lane>>4.
    const int wcol = wt * WT + wave * 16 + c;
    const int wrow = word_seq[b * WW + wcol];
    const float4* ap = reinterpret_cast<const float4*>(
        hidden + ((size_t)(b * LL) + l0 + c) * HH + g * 8);   // stride 8/f4 per k
    const float4* bp = reinterpret_cast<const float4*>(
        emb_a + (size_t)wrow * HH + g * 8);

    // Depth-4 rotating prefetch buffers (statically indexed after unroll).
    float4 ra0[4], ra1[4], rb0[4], rb1[4];
    #pragma unroll
    for (int i = 0; i < 4; ++i) {
        ra0[i] = ap[i * 8];  ra1[i] = ap[i * 8 + 1];
        rb0[i] = bp[i * 8];  rb1[i] = bp[i * 8 + 1];
    }

    f32x4 acc = {0.f, 0.f, 0.f, 0.f};
    #pragma unroll
    for (int k = 0; k < 24; ++k) {
        const int slot = k & 3;
        bf16x8 a  = pack8(ra0[slot], ra1[slot]);
        bf16x8 bv = pack8(rb0[slot], rb1[slot]);
        if (k + 4 < 24) {   // issue next loads into the freed slot
            ra0[slot] = ap[(k + 4) * 8];  ra1[slot] = ap[(k + 4) * 8 + 1];
            rb0[slot] = bp[(k + 4) * 8];  rb1[slot] = bp[(k + 4) * 8 + 1];
        }
        acc = __builtin_amdgcn_mfma_f32_16x16x32_bf16(a, bv, acc, 0, 0, 0);
    }
    __syncthreads();   // s_lds zeros visible

    // C/D layout (m89): col = lane&15, row = (lane>>4)*4 + reg
    const float scale = 0.03608439182435161f;  // 1/sqrt(768)
    #pragma unroll
    for (int r = 0; r < 4; ++r) {
        int lrow = g * 4 + r;
        size_t idx = ((size_t)(b * LL) + l0 + lrow) * WW + wcol;
        float m = mask[idx];
        m = fminf(fmaxf(m, 0.f), 1.f);
        float e = __expf(acc[r] * scale) * m;
        atomicAdd(&s_lds[lrow][label[idx]], e);
    }
    __syncthreads();

    if (t < LT * NL)
        s_out[(size_t)bid * (LT * NL) + t] = ((float*)s_lds)[t];
}

// ---------------------------------------------------------------------------
// K2: combine W-tile partials, normalize, 10-row epilogue + residual.
// Block = (b, 16 L-rows, 192 h-cols); grid 256, 192 threads (3 waves).
// ---------------------------------------------------------------------------
__global__ __launch_bounds__(192, 4) void combine_kernel(
    const float* __restrict__ s_in,     // [256][16][10]
    const float* __restrict__ hidden,   // [B,L,H]
    const float* __restrict__ emb_c,    // [10,H]
    float* __restrict__ out)            // [B,L,H]
{
    __shared__ float sp[LT][NL];
    __shared__ float inv[LT];
    const int t = threadIdx.x;
    const int bid = blockIdx.x;
    const int hq = bid & 3, lt = (bid >> 2) & 15, b = bid >> 6;
    const int l0 = lt * LT;
    const int h = hq * 192 + t;

    if (t < LT * NL) {
        size_t base = ((size_t)(b * 16 + lt)) * 4 * (LT * NL);  // wt=0 slot
        float v = 0.f;
        #pragma unroll
        for (int wt = 0; wt < 4; ++wt) v += s_in[base + wt * (LT * NL) + t];
        ((float*)sp)[t] = v;
    }
    __syncthreads();
    if (t < LT) {
        float d = 1e-10f;
        #pragma unroll
        for (int k = 0; k < NL; ++k) d += sp[t][k];
        inv[t] = 1.f / d;
    }
    __syncthreads();

    float ec[NL];
    #pragma unroll
    for (int k = 0; k < NL; ++k) ec[k] = emb_c[k * HH + h];
    #pragma unroll
    for (int r = 0; r < LT; ++r) {
        size_t base = ((size_t)(b * LL) + l0 + r) * HH + h;
        float acc = 0.f;
        #pragma unroll
        for (int k = 0; k < NL; ++k) acc = fmaf(sp[r][k], ec[k], acc);
        out[base] = hidden[base] + acc * inv[r];
    }
}

extern "C" void kernel_launch(void* const* d_in, const int* in_sizes, int n_in,
                              void* d_out, int out_size, void* d_ws, size_t ws_size,
                              hipStream_t stream) {
    const int*   word_seq = (const int*)d_in[0];
    const float* hidden   = (const float*)d_in[1];
    const int*   label    = (const int*)d_in[2];
    const float* mask     = (const float*)d_in[3];
    const float* emb_a    = (const float*)d_in[4];
    const float* emb_c    = (const float*)d_in[5];
    float*       out      = (float*)d_out;

    float* s_out = (float*)d_ws;   // 256*160 fp32 = 160 KB scratch

    score_kernel<<<BB * 16 * 4, 256, 0, stream>>>(
        word_seq, hidden, emb_a, label, mask, s_out);
    combine_kernel<<<BB * 16 * 4, 192, 0, stream>>>(s_out, hidden, emb_c, out);
}